// Round 11
// baseline (268.384 us; speedup 1.0000x reference)
//
#include <hip/hip_runtime.h>

// RIIDModelLSTM: 2-layer LSTM (H=6), T=512, B=8192, fused FC(6->32->1) head.
//
// v11 = v7's 16-lane/2-waves-per-SIMD mapping + v6/v10's pk-asm engine.
// Ledger: v10 (8-lane, 1 wave/SIMD) = 849 cyc/step: 658 busy (at issue floor)
// + 190 unfillable stall. pk_fma = 2x scalar cycles (R5/R6: FLOP-bound), so
// FMA cycles/SIMD are mapping-invariant (240); the win of 16 lanes/seq is
// per-wave issue halves and the SIBLING WAVE fills all latency windows.
// v7's regression was scalar math + duplicated glue; v11 packs each lane's
// gate pair as one v2f (30 pk/step vs v7's 66 scalar) and drops the
// x-hoist/rotation machinery (cross-wave hiding replaces it).
//
// Layout per 16-lane row (= 1 seq; 4 seqs/wave, 2048 waves = 2/SIMD):
//   l=L&15; half=l>>3 (0:[i,f], 1:[g,o]); k=l&7 (unit; 6,7 pad, zero wts).
//   act f(a) = 1 + negB*rcp(1+2^a); scales (L2E / 2*L2E) folded into weights;
//   sigmoid negB=-1, tanh negB=-2. (v7-verified numerics, absmax 2.44e-4.)
//   gate swap: row_ror:8; h gather: ror12 + 2 cndmask + 6 quad bcasts
//   (HW-verified in v7); FC reduce: 4 DPP-fused rotate-adds over the row.

typedef float v2f __attribute__((ext_vector_type(2)));

static constexpr float L2E  = 1.44269504088896340736f;
static constexpr float TL2E = 2.0f * L2E;

#define DPP_QP(a,b,c,d) ((a)|((b)<<2)|((c)<<4)|((d)<<6))
#define DPP_B0  DPP_QP(0,0,0,0)   // quad bcast lane0
#define DPP_B1  DPP_QP(1,1,1,1)
#define DPP_B2  DPP_QP(2,2,2,2)
#define DPP_B3  DPP_QP(3,3,3,3)
#define DPP_R1  0x121             // row_ror:1
#define DPP_R2  0x122             // row_ror:2
#define DPP_R4  0x124             // row_ror:4
#define DPP_R8  0x128             // row_ror:8 (= lane xor 8 in 16-row)
#define DPP_R12 0x12C             // row_ror:12

template<int CTRL>
__device__ __forceinline__ float dppf(float v) {
    return __int_as_float(__builtin_amdgcn_update_dpp(
        0, __float_as_int(v), CTRL, 0xF, 0xF, true));
}

#define PIN(v) asm volatile("" : "+v"(v))

// d += a * (b.lo, b.lo)
#define PKFMA_LO(d,a,b) asm("v_pk_fma_f32 %0, %1, %2, %0 op_sel:[0,0,0] op_sel_hi:[1,0,1]" : "+v"(d) : "v"(a), "v"(b))
// d += a * (b.hi, b.hi)
#define PKFMA_HI(d,a,b) asm("v_pk_fma_f32 %0, %1, %2, %0 op_sel:[0,1,0] op_sel_hi:[1,1,1]" : "+v"(d) : "v"(a), "v"(b))
#define PKADD(d,a,b)    asm("v_pk_add_f32 %0, %1, %2" : "=v"(d) : "v"(a), "v"(b))

// f(a) = 1 + negB * rcp(1 + 2^a); scale pre-folded (positive: L2E / 2*L2E).
// sigmoid: negB=-1 -> e^x/(1+e^x); tanh: negB=-2 -> 1-2/(1+e^{2x}).
__device__ __forceinline__ float act_pre(float a, float negB) {
    return fmaf(negB, __builtin_amdgcn_rcpf(1.0f + __builtin_amdgcn_exp2f(a)), 1.0f);
}

extern "C" __global__ void __launch_bounds__(64)
__attribute__((amdgpu_waves_per_eu(2, 2)))
lstm16pk(const float* __restrict__ x,
         const float* __restrict__ wih0, const float* __restrict__ whh0,
         const float* __restrict__ bih0, const float* __restrict__ bhh0,
         const float* __restrict__ wih1, const float* __restrict__ whh1,
         const float* __restrict__ bih1, const float* __restrict__ bhh1,
         const float* __restrict__ fc1w, const float* __restrict__ fc1b,
         const float* __restrict__ fc2w, const float* __restrict__ fc2b,
         float* __restrict__ out, int nbatch)
{
    const int L    = threadIdx.x;                // 0..63
    const int l    = L & 15;                     // lane in row
    const int half = l >> 3;                     // 0: [i,f]; 1: [g,o]
    const int k    = l & 7;                      // unit (6,7 pad)
    const bool qe  = ((l >> 2) & 1) == 0;        // quads 0,2 own units 0-3

    int seq = blockIdx.x * 4 + (L >> 4);
    if (seq >= nbatch) seq = nbatch - 1;         // 8192 % 4 == 0: all live

    const float km = (k < 6) ? 1.0f : 0.0f;
    const int   kk = (k < 6) ? k : 0;

    const int r1 = (half ? 12 : 0) + kk;         // gate1 row: i or g
    const int r2 = (half ? 18 : 6) + kk;         // gate2 row: f or o
    const float s1 = km * (half ? TL2E : L2E);   // gate1 act scale
    const float s2 = km * L2E;                   // gate2 always sigmoid
    const float negB1 = half ? -2.0f : -1.0f;

    // ---- per-lane weights: ONE gate pair, packed as v2f (24 v2f = 48 regs)
    v2f wi0[6], wh0[6], wi1[6], wh1[6], f1w[6];
#pragma unroll
    for (int j = 0; j < 6; ++j) {
        wi0[j] = (v2f){ wih0[r1 * 6 + j] * s1, wih0[r2 * 6 + j] * s2 };
        wh0[j] = (v2f){ whh0[r1 * 6 + j] * s1, whh0[r2 * 6 + j] * s2 };
        wi1[j] = (v2f){ wih1[r1 * 6 + j] * s1, wih1[r2 * 6 + j] * s2 };
        wh1[j] = (v2f){ whh1[r1 * 6 + j] * s1, whh1[r2 * 6 + j] * s2 };
        f1w[j] = (v2f){ fc1w[(2 * l) * 6 + j], fc1w[(2 * l + 1) * 6 + j] };
    }
    v2f bb0 = (v2f){ (bih0[r1] + bhh0[r1]) * s1, (bih0[r2] + bhh0[r2]) * s2 };
    v2f bb1 = (v2f){ (bih1[r1] + bhh1[r1]) * s1, (bih1[r2] + bhh1[r2]) * s2 };
    v2f f1b = (v2f){ fc1b[2 * l], fc1b[2 * l + 1] };
    v2f f2w = (v2f){ fc2w[2 * l], fc2w[2 * l + 1] };
    const float f2b = fc2b[0];

#pragma unroll
    for (int j = 0; j < 6; ++j) {
        PIN(wi0[j]); PIN(wh0[j]); PIN(wi1[j]); PIN(wh1[j]); PIN(f1w[j]);
    }
    PIN(bb0); PIN(bb1); PIN(f1b); PIN(f2w);

    // ---- state: h packed pairwise unit-ordered, c per lane
    v2f h0p[3], h1p[3];
    const v2f Z2 = (v2f){0.0f, 0.0f};
#pragma unroll
    for (int q = 0; q < 3; ++q) { h0p[q] = Z2; h1p[q] = Z2; }
    float c0 = 0.0f, c1 = 0.0f;

    const float* xp = x + (size_t)seq * 3072;
    float*       op = out + (size_t)seq * 512;

    // ---- 2-deep x prefetch (3 v2f per step; row-uniform loads -> L1 bcast)
    v2f xqA[3], xqB[3];
    xqA[0] = *(const v2f*)(xp + 0); xqA[1] = *(const v2f*)(xp + 2); xqA[2] = *(const v2f*)(xp + 4);
    xqB[0] = *(const v2f*)(xp + 6); xqB[1] = *(const v2f*)(xp + 8); xqB[2] = *(const v2f*)(xp + 10);

    // unit-ordered gather: h[unit j] -> slot pair on every lane (v7-verified)
#define GATHER(HP_, HV_)                                                        \
    {                                                                           \
        float u_  = dppf<DPP_R12>(HV_);                                         \
        float hl_ = qe ? (HV_) : u_;             /* units 0-3 @ quad pos */     \
        float hh_ = qe ? u_ : (HV_);             /* units 4-7 @ quad pos */     \
        HP_[0] = (v2f){ dppf<DPP_B0>(hl_), dppf<DPP_B1>(hl_) };                 \
        HP_[1] = (v2f){ dppf<DPP_B2>(hl_), dppf<DPP_B3>(hl_) };                 \
        HP_[2] = (v2f){ dppf<DPP_B0>(hh_), dppf<DPP_B1>(hh_) };                 \
    }

#define STEP(XC_, TP_, YV_)                                                     \
    {                                                                           \
        const float* xr_ = xp + (TP_) * 6;                                      \
        v2f nx0_ = *(const v2f*)(xr_ + 0);                                      \
        v2f nx1_ = *(const v2f*)(xr_ + 2);                                      \
        v2f nx2_ = *(const v2f*)(xr_ + 4);                                      \
        /* cell 0 gates: x-part + h-part, dual pk accumulators */               \
        v2f aP_ = bb0, aQ_ = Z2;                                                \
        PKFMA_LO(aP_, wi0[0], XC_[0]); PKFMA_HI(aQ_, wi0[1], XC_[0]);           \
        PKFMA_LO(aP_, wi0[2], XC_[1]); PKFMA_HI(aQ_, wi0[3], XC_[1]);           \
        PKFMA_LO(aP_, wi0[4], XC_[2]); PKFMA_HI(aQ_, wi0[5], XC_[2]);           \
        PKFMA_LO(aP_, wh0[0], h0p[0]); PKFMA_HI(aQ_, wh0[1], h0p[0]);           \
        PKFMA_LO(aP_, wh0[2], h0p[1]); PKFMA_HI(aQ_, wh0[3], h0p[1]);           \
        PKFMA_LO(aP_, wh0[4], h0p[2]); PKFMA_HI(aQ_, wh0[5], h0p[2]);           \
        v2f g0_;                                                                \
        PKADD(g0_, aP_, aQ_);                                                   \
        float A1_ = act_pre(g0_.x, negB1);       /* i (half0) | g (half1) */    \
        float A2_ = act_pre(g0_.y, -1.0f);       /* f (half0) | o (half1) */    \
        float S1_ = dppf<DPP_R8>(A1_);                                          \
        float S2_ = dppf<DPP_R8>(A2_);                                          \
        float fv_ = half ? S2_ : A2_;                                           \
        float ov_ = half ? A2_ : S2_;                                           \
        c0 = fmaf(fv_, c0, A1_ * S1_);           /* A1*S1 == i*g both halves */ \
        float h0_ = ov_ * act_pre(TL2E * c0, -2.0f);                            \
        GATHER(h0p, h0_);                                                       \
        /* cell 1 gates: h1-part + fresh-h0 part */                             \
        v2f pP_ = bb1, pQ_ = Z2;                                                \
        PKFMA_LO(pP_, wh1[0], h1p[0]); PKFMA_HI(pQ_, wh1[1], h1p[0]);           \
        PKFMA_LO(pP_, wh1[2], h1p[1]); PKFMA_HI(pQ_, wh1[3], h1p[1]);           \
        PKFMA_LO(pP_, wh1[4], h1p[2]); PKFMA_HI(pQ_, wh1[5], h1p[2]);           \
        PKFMA_LO(pP_, wi1[0], h0p[0]); PKFMA_HI(pQ_, wi1[1], h0p[0]);           \
        PKFMA_LO(pP_, wi1[2], h0p[1]); PKFMA_HI(pQ_, wi1[3], h0p[1]);           \
        PKFMA_LO(pP_, wi1[4], h0p[2]); PKFMA_HI(pQ_, wi1[5], h0p[2]);           \
        v2f g1_;                                                                \
        PKADD(g1_, pP_, pQ_);                                                   \
        float B1_ = act_pre(g1_.x, negB1);                                      \
        float B2_ = act_pre(g1_.y, -1.0f);                                      \
        float T1_ = dppf<DPP_R8>(B1_);                                          \
        float T2_ = dppf<DPP_R8>(B2_);                                          \
        float fw_ = half ? T2_ : B2_;                                           \
        float ow_ = half ? B2_ : T2_;                                           \
        c1 = fmaf(fw_, c1, B1_ * T1_);                                          \
        float h1_ = ow_ * act_pre(TL2E * c1, -2.0f);                            \
        GATHER(h1p, h1_);                                                       \
        /* FC head: rows 2l, 2l+1; rotate-add reduce over the 16-lane row */    \
        v2f rP_ = f1b, rQ_ = Z2;                                                \
        PKFMA_LO(rP_, f1w[0], h1p[0]); PKFMA_HI(rQ_, f1w[1], h1p[0]);           \
        PKFMA_LO(rP_, f1w[2], h1p[1]); PKFMA_HI(rQ_, f1w[3], h1p[1]);           \
        PKFMA_LO(rP_, f1w[4], h1p[2]); PKFMA_HI(rQ_, f1w[5], h1p[2]);           \
        v2f R_;                                                                 \
        PKADD(R_, rP_, rQ_);                                                    \
        float acc_ = fmaxf(R_.x, 0.0f) * f2w.x;                                 \
        acc_ = fmaf(fmaxf(R_.y, 0.0f), f2w.y, acc_);                            \
        acc_ += dppf<DPP_R1>(acc_);                                             \
        acc_ += dppf<DPP_R2>(acc_);                                             \
        acc_ += dppf<DPP_R4>(acc_);                                             \
        acc_ += dppf<DPP_R8>(acc_);                                             \
        YV_ = fmaxf(acc_ + f2b, 0.0f);                                          \
        XC_[0] = nx0_; XC_[1] = nx1_; XC_[2] = nx2_;                            \
    }

    for (int t = 0; t < 512; t += 2) {
        float y0_, y1_;
        STEP(xqA, (t + 2 < 512 ? t + 2 : 510), y0_);
        STEP(xqB, (t + 3 < 512 ? t + 3 : 511), y1_);
        if ((L & 15) == 0) *(float2*)(op + t) = make_float2(y0_, y1_);
    }
#undef STEP
#undef GATHER
}

extern "C" void kernel_launch(void* const* d_in, const int* in_sizes, int n_in,
                              void* d_out, int out_size, void* d_ws, size_t ws_size,
                              hipStream_t stream) {
    const float* x     = (const float*)d_in[0];
    const float* wih0  = (const float*)d_in[1];
    const float* whh0  = (const float*)d_in[2];
    const float* bih0  = (const float*)d_in[3];
    const float* bhh0  = (const float*)d_in[4];
    const float* wih1  = (const float*)d_in[5];
    const float* whh1  = (const float*)d_in[6];
    const float* bih1  = (const float*)d_in[7];
    const float* bhh1  = (const float*)d_in[8];
    const float* fc1w  = (const float*)d_in[9];
    const float* fc1b  = (const float*)d_in[10];
    const float* fc2w  = (const float*)d_in[11];
    const float* fc2b  = (const float*)d_in[12];
    float* out = (float*)d_out;

    const int nbatch = in_sizes[0] / (512 * 6);     // 8192
    const int grid   = (nbatch + 3) / 4;            // 4 seqs per 64-thread wave

    hipLaunchKernelGGL(lstm16pk, dim3(grid), dim3(64), 0, stream,
                       x, wih0, whh0, bih0, bhh0, wih1, whh1, bih1, bhh1,
                       fc1w, fc1b, fc2w, fc2b, out, nbatch);
}

// Round 12
// 184.208 us; speedup vs baseline: 1.4570x; 1.4570x over previous
//
#include <hip/hip_runtime.h>

// RIIDModelLSTM: 2-layer LSTM (H=6), T=512, B=8192, fused FC(6->32->1) head.
//
// v12 = v10 (181.2us) + ONE-STEP FC DEFERRAL.
// Ledger: v10 = 849 cyc/step = 658 busy (issue floor) + 190 bubbles.
// R11 proved 16-lane/2-wave mapping is structurally worse (per-instruction
// wave-wide costs don't divide; 1046 vs 658 busy per 8 seqs) -> 8-lane,
// 1 wave/SIMD is optimal. The tanh(c0) latency window (~70cyc) had ZERO
// independent filler because FC(t) depends on h1(t), the last value of the
// step. v12 computes FC(t-1) there instead -- h1p still holds h1(t-1) until
// step t's GATHER overwrites it. Dataflow change the scheduler can't do
// itself; outputs bit-identical, shifted bookkeeping + epilogue FC.
// Mapping unchanged: 8-lane coset/seq, p=(l&3)|((l>>3)<<2), zero-DS,
// DPP-only, pk-asm math, 1024 waves = 1/SIMD.

typedef float v2f __attribute__((ext_vector_type(2)));

static constexpr float L2E  = 1.44269504088896340736f;
static constexpr float TL2E = 2.0f * L2E;

#define DPP_QP(a,b,c,d) ((a)|((b)<<2)|((c)<<4)|((d)<<6))
#define DPP_X1  DPP_QP(1,0,3,2)   // quad_perm xor-1
#define DPP_X2  DPP_QP(2,3,0,1)   // quad_perm xor-2
#define DPP_B0  DPP_QP(0,0,0,0)   // quad bcast lane0
#define DPP_B1  DPP_QP(1,1,1,1)
#define DPP_B2  DPP_QP(2,2,2,2)
#define DPP_B3  DPP_QP(3,3,3,3)
#define DPP_X8  0x128             // row_ror:8 = lane xor 8 inside 16-row

template<int CTRL>
__device__ __forceinline__ float dppf(float v) {
    return __int_as_float(__builtin_amdgcn_update_dpp(
        0, __float_as_int(v), CTRL, 0xF, 0xF, true));
}

#define PIN(v) asm volatile("" : "+v"(v))

// d += a * (b.lo, b.lo)   [VOP3P op_sel: src1 lo for both halves]
#define PKFMA_LO(d,a,b) asm("v_pk_fma_f32 %0, %1, %2, %0 op_sel:[0,0,0] op_sel_hi:[1,0,1]" : "+v"(d) : "v"(a), "v"(b))
// d += a * (b.hi, b.hi)
#define PKFMA_HI(d,a,b) asm("v_pk_fma_f32 %0, %1, %2, %0 op_sel:[0,1,0] op_sel_hi:[1,1,1]" : "+v"(d) : "v"(a), "v"(b))
#define PKADD(d,a,b)    asm("v_pk_add_f32 %0, %1, %2" : "=v"(d) : "v"(a), "v"(b))

// sigmoid with -L2E pre-folded into weights:  a = -L2E*x -> 1/(1+2^a)
__device__ __forceinline__ float sig_pre(float a) {
    return __builtin_amdgcn_rcpf(1.0f + __builtin_amdgcn_exp2f(a));
}
// tanh with +2*L2E pre-folded:  a = 2*L2E*x -> tanh(x) = 1 - 2/(1+2^a)
__device__ __forceinline__ float tanh_pre(float a) {
    return fmaf(-2.0f, __builtin_amdgcn_rcpf(1.0f + __builtin_amdgcn_exp2f(a)), 1.0f);
}

extern "C" __global__ void __launch_bounds__(64)
__attribute__((amdgpu_waves_per_eu(1, 1)))
lstm_dpp8v12(const float* __restrict__ x,
             const float* __restrict__ wih0, const float* __restrict__ whh0,
             const float* __restrict__ bih0, const float* __restrict__ bhh0,
             const float* __restrict__ wih1, const float* __restrict__ whh1,
             const float* __restrict__ bih1, const float* __restrict__ bhh1,
             const float* __restrict__ fc1w, const float* __restrict__ fc1b,
             const float* __restrict__ fc2w, const float* __restrict__ fc2b,
             float* __restrict__ out, int nbatch)
{
    const int L   = threadIdx.x;                 // 0..63
    const int l   = L & 15;
    const int row = L >> 4;                      // 0..3
    const int cst = (l >> 2) & 1;                // coset within row
    const int p   = (l & 3) | ((l >> 3) << 2);   // position in coset, 0..7
    const bool lowq = ((L >> 3) & 1) == 0;       // lane in units-0..3 quad

    int seq = blockIdx.x * 8 + row * 2 + cst;
    const bool live = (seq < nbatch);
    if (!live) seq = nbatch - 1;

    const float km = (p < 6) ? 1.0f : 0.0f;      // pad lanes 6,7
    const int   k  = (p < 6) ? p : 0;
    const int ir = k, fr = 6 + k, gr = 12 + k, orr = 18 + k;  // i,f,g,o rows

    // ---- weights. Gate pairs A=[i,f] (sigmoid,-L2E | sigmoid,-L2E),
    //               B=[g,o] (tanh,+2L2E | sigmoid,-L2E). Unit-ordered slots.
    v2f wiA0[6], wiB0[6];
    v2f whA0[6], whB0[6], wiA1[6], wiB1[6], whA1[6], whB1[6], f1wA[6], f1wB[6];
#pragma unroll
    for (int j = 0; j < 6; ++j) {
        wiA0[j] = (v2f){ wih0[ir*6+j]*(-L2E)*km,  wih0[fr*6+j]*(-L2E)*km };
        wiB0[j] = (v2f){ wih0[gr*6+j]*( TL2E)*km, wih0[orr*6+j]*(-L2E)*km };
        whA0[j] = (v2f){ whh0[ir*6+j]*(-L2E)*km,  whh0[fr*6+j]*(-L2E)*km };
        whB0[j] = (v2f){ whh0[gr*6+j]*( TL2E)*km, whh0[orr*6+j]*(-L2E)*km };
        wiA1[j] = (v2f){ wih1[ir*6+j]*(-L2E)*km,  wih1[fr*6+j]*(-L2E)*km };
        wiB1[j] = (v2f){ wih1[gr*6+j]*( TL2E)*km, wih1[orr*6+j]*(-L2E)*km };
        whA1[j] = (v2f){ whh1[ir*6+j]*(-L2E)*km,  whh1[fr*6+j]*(-L2E)*km };
        whB1[j] = (v2f){ whh1[gr*6+j]*( TL2E)*km, whh1[orr*6+j]*(-L2E)*km };
        f1wA[j] = (v2f){ fc1w[(4*p+0)*6+j], fc1w[(4*p+1)*6+j] };
        f1wB[j] = (v2f){ fc1w[(4*p+2)*6+j], fc1w[(4*p+3)*6+j] };
    }
    v2f bbA0 = (v2f){ (bih0[ir]+bhh0[ir])*(-L2E)*km,  (bih0[fr]+bhh0[fr])*(-L2E)*km };
    v2f bbB0 = (v2f){ (bih0[gr]+bhh0[gr])*( TL2E)*km, (bih0[orr]+bhh0[orr])*(-L2E)*km };
    v2f bbA1 = (v2f){ (bih1[ir]+bhh1[ir])*(-L2E)*km,  (bih1[fr]+bhh1[fr])*(-L2E)*km };
    v2f bbB1 = (v2f){ (bih1[gr]+bhh1[gr])*( TL2E)*km, (bih1[orr]+bhh1[orr])*(-L2E)*km };
    v2f f1bA = (v2f){ fc1b[4*p+0], fc1b[4*p+1] };
    v2f f1bB = (v2f){ fc1b[4*p+2], fc1b[4*p+3] };
    v2f f2wA = (v2f){ fc2w[4*p+0], fc2w[4*p+1] };
    v2f f2wB = (v2f){ fc2w[4*p+2], fc2w[4*p+3] };
    float f2b = fc2b[0];

#pragma unroll
    for (int j = 0; j < 6; ++j) {
        PIN(wiA0[j]); PIN(wiB0[j]); PIN(whA0[j]); PIN(whB0[j]);
        PIN(wiA1[j]); PIN(wiB1[j]); PIN(whA1[j]); PIN(whB1[j]);
        PIN(f1wA[j]); PIN(f1wB[j]);
    }
    PIN(bbA0); PIN(bbB0); PIN(bbA1); PIN(bbB1);
    PIN(f1bA); PIN(f1bB); PIN(f2wA); PIN(f2wB); PIN(f2b);

    // ---- state: h packed pairwise, units (0,1),(2,3),(4,5)
    v2f h0p[3], h1p[3];
    const v2f Z2 = (v2f){0.0f, 0.0f};
#pragma unroll
    for (int q = 0; q < 3; ++q) { h0p[q] = Z2; h1p[q] = Z2; }
    float c0 = 0.0f, c1 = 0.0f;

    const float* xp = x + (size_t)seq * (512 * 6);
    float*       op = out + (size_t)seq * 512;

    // ---- 4-deep x prefetch, pairs (x0,x1),(x2,x3),(x4,x5) as v2f
    v2f xq[4][3];
#pragma unroll
    for (int j = 0; j < 4; ++j) {
        const float* q = xp + j * 6;
        xq[j][0] = *(const v2f*)(q + 0);
        xq[j][1] = *(const v2f*)(q + 2);
        xq[j][2] = *(const v2f*)(q + 4);
    }

    // unit-ordered gather: h[unit j] -> slot j on every lane, 6 slots
#define GATHER(HP_, HV_)                                                        \
    {                                                                           \
        float u_ = dppf<DPP_X8>(HV_);            /* partner quad's h */         \
        float hl = lowq ? (HV_) : u_;            /* units 0-3 @ quad pos */     \
        float hh = lowq ? u_ : (HV_);            /* units 4-7 @ quad pos */     \
        HP_[0] = (v2f){ dppf<DPP_B0>(hl), dppf<DPP_B1>(hl) };                   \
        HP_[1] = (v2f){ dppf<DPP_B2>(hl), dppf<DPP_B3>(hl) };                   \
        HP_[2] = (v2f){ dppf<DPP_B0>(hh), dppf<DPP_B1>(hh) };                   \
    }

    // FC head on h1p (whatever step's h1 it currently holds); yields scalar y
#define FC_BLOCK(YDST_)                                                         \
    {                                                                           \
        v2f rA = f1bA, rA2 = Z2, rB = f1bB, rB2 = Z2;                           \
        PKFMA_LO(rA, f1wA[0], h1p[0]); PKFMA_HI(rA2, f1wA[1], h1p[0]);          \
        PKFMA_LO(rA, f1wA[2], h1p[1]); PKFMA_HI(rA2, f1wA[3], h1p[1]);          \
        PKFMA_LO(rA, f1wA[4], h1p[2]); PKFMA_HI(rA2, f1wA[5], h1p[2]);          \
        PKFMA_LO(rB, f1wB[0], h1p[0]); PKFMA_HI(rB2, f1wB[1], h1p[0]);          \
        PKFMA_LO(rB, f1wB[2], h1p[1]); PKFMA_HI(rB2, f1wB[3], h1p[1]);          \
        PKFMA_LO(rB, f1wB[4], h1p[2]); PKFMA_HI(rB2, f1wB[5], h1p[2]);          \
        v2f RA, RB;                                                             \
        PKADD(RA, rA, rA2);                                                     \
        PKADD(RB, rB, rB2);                                                     \
        float acc =          fmaxf(RA.x, 0.0f) * f2wA.x;                        \
        acc = fmaf(fmaxf(RA.y, 0.0f), f2wA.y, acc);                             \
        acc = fmaf(fmaxf(RB.x, 0.0f), f2wB.x, acc);                             \
        acc = fmaf(fmaxf(RB.y, 0.0f), f2wB.y, acc);                             \
        acc += dppf<DPP_X1>(acc);                                               \
        acc += dppf<DPP_X2>(acc);                                               \
        acc += dppf<DPP_X8>(acc);                                               \
        YDST_ = fmaxf(acc + f2b, 0.0f);                                         \
    }

    // ---- cell0 FULL gate-preactivation accumulators for the CURRENT step.
    v2f xgA, xgA2, xgB, xgB2;
    {
        xgA = bbA0; xgA2 = Z2; xgB = bbB0; xgB2 = Z2;
        PKFMA_LO(xgA, wiA0[0], xq[0][0]); PKFMA_HI(xgA2, wiA0[1], xq[0][0]);
        PKFMA_LO(xgA, wiA0[2], xq[0][1]); PKFMA_HI(xgA2, wiA0[3], xq[0][1]);
        PKFMA_LO(xgA, wiA0[4], xq[0][2]); PKFMA_HI(xgA2, wiA0[5], xq[0][2]);
        PKFMA_LO(xgB, wiB0[0], xq[0][0]); PKFMA_HI(xgB2, wiB0[1], xq[0][0]);
        PKFMA_LO(xgB, wiB0[2], xq[0][1]); PKFMA_HI(xgB2, wiB0[3], xq[0][1]);
        PKFMA_LO(xgB, wiB0[4], xq[0][2]); PKFMA_HI(xgB2, wiB0[5], xq[0][2]);
    }

    // ybuf[s] holds y(g) for the most recent g with g%4 == s.
    float ybuf[4] = {0.0f, 0.0f, 0.0f, 0.0f};

    for (int T = 0; T < 512; T += 4) {
        const int Tn = (T < 508) ? T + 4 : 508;   // clamped prefetch base
#pragma unroll
        for (int j = 0; j < 4; ++j) {
            // -- issue x[T+j+4] loads early (consumed next outer iter)
            const float* xr = xp + (Tn + j) * 6;
            v2f nx0 = *(const v2f*)(xr + 0);
            v2f nx1 = *(const v2f*)(xr + 2);
            v2f nx2 = *(const v2f*)(xr + 4);

            // -- gates0 close IMMEDIATELY (xg* holds bias+x+wh parts)
            v2f gA0, gB0;
            PKADD(gA0, xgA, xgA2);
            PKADD(gB0, xgB, xgB2);

            float i0 = sig_pre(gA0.x), f0 = sig_pre(gA0.y);
            float g0 = tanh_pre(gB0.x), o0 = sig_pre(gB0.y);

            // -- act0-window filler 1: cell1 recurrent partial (h1p(t-1))
            v2f pA = bbA1, pA2 = Z2, pB = bbB1, pB2 = Z2;
            PKFMA_LO(pA, whA1[0], h1p[0]); PKFMA_HI(pA2, whA1[1], h1p[0]);
            PKFMA_LO(pA, whA1[2], h1p[1]); PKFMA_HI(pA2, whA1[3], h1p[1]);
            PKFMA_LO(pA, whA1[4], h1p[2]); PKFMA_HI(pA2, whA1[5], h1p[2]);
            PKFMA_LO(pB, whB1[0], h1p[0]); PKFMA_HI(pB2, whB1[1], h1p[0]);
            PKFMA_LO(pB, whB1[2], h1p[1]); PKFMA_HI(pB2, whB1[3], h1p[1]);
            PKFMA_LO(pB, whB1[4], h1p[2]); PKFMA_HI(pB2, whB1[5], h1p[2]);

            // -- act0-window filler 2: x-part of gates0(t+1) into fresh regs
            {
                const v2f* xn = xq[(j + 1) & 3];
                v2f tA = bbA0, tA2 = Z2, tB = bbB0, tB2 = Z2;
                PKFMA_LO(tA, wiA0[0], xn[0]); PKFMA_HI(tA2, wiA0[1], xn[0]);
                PKFMA_LO(tA, wiA0[2], xn[1]); PKFMA_HI(tA2, wiA0[3], xn[1]);
                PKFMA_LO(tA, wiA0[4], xn[2]); PKFMA_HI(tA2, wiA0[5], xn[2]);
                PKFMA_LO(tB, wiB0[0], xn[0]); PKFMA_HI(tB2, wiB0[1], xn[0]);
                PKFMA_LO(tB, wiB0[2], xn[1]); PKFMA_HI(tB2, wiB0[3], xn[1]);
                PKFMA_LO(tB, wiB0[4], xn[2]); PKFMA_HI(tB2, wiB0[5], xn[2]);
                xgA = tA; xgA2 = tA2; xgB = tB; xgB2 = tB2;
            }

            c0 = fmaf(f0, c0, i0 * g0);
            float th0 = tanh_pre(TL2E * c0);

            // -- tanh(c0)-window filler (THE v12 change): DEFERRED FC on
            //    h1p, which still holds h1(t-1). Independent of this step's
            //    entire recurrence. y(t-1) -> slot (t-1)%4 = (j+3)&3.
            FC_BLOCK(ybuf[(j + 3) & 3]);
            if (j == 0) {
                // ybuf now holds y(T-4..T-1) in slots 0..3
                if (T > 0 && live && ((L & 11) == 0)) {
                    float4 yv = make_float4(ybuf[0], ybuf[1], ybuf[2], ybuf[3]);
                    *(float4*)(op + T - 4) = yv;
                }
            }

            float h0 = o0 * th0;
            GATHER(h0p, h0);

            // -- cell 1 finish (input part over fresh h0)
            PKFMA_LO(pA, wiA1[0], h0p[0]); PKFMA_HI(pA2, wiA1[1], h0p[0]);
            PKFMA_LO(pA, wiA1[2], h0p[1]); PKFMA_HI(pA2, wiA1[3], h0p[1]);
            PKFMA_LO(pA, wiA1[4], h0p[2]); PKFMA_HI(pA2, wiA1[5], h0p[2]);
            PKFMA_LO(pB, wiB1[0], h0p[0]); PKFMA_HI(pB2, wiB1[1], h0p[0]);
            PKFMA_LO(pB, wiB1[2], h0p[1]); PKFMA_HI(pB2, wiB1[3], h0p[1]);
            PKFMA_LO(pB, wiB1[4], h0p[2]); PKFMA_HI(pB2, wiB1[5], h0p[2]);
            v2f gA1, gB1;
            PKADD(gA1, pA, pA2);
            PKADD(gB1, pB, pB2);

            float i1 = sig_pre(gA1.x), f1 = sig_pre(gA1.y);
            float g1 = tanh_pre(gB1.x), o1 = sig_pre(gB1.y);

            // -- act1-window filler: wh-part of gates0(t+1) (h0p = h0(t))
            PKFMA_LO(xgA, whA0[0], h0p[0]);  PKFMA_HI(xgA2, whA0[1], h0p[0]);
            PKFMA_LO(xgA, whA0[2], h0p[1]);  PKFMA_HI(xgA2, whA0[3], h0p[1]);
            PKFMA_LO(xgA, whA0[4], h0p[2]);  PKFMA_HI(xgA2, whA0[5], h0p[2]);
            PKFMA_LO(xgB, whB0[0], h0p[0]);  PKFMA_HI(xgB2, whB0[1], h0p[0]);
            PKFMA_LO(xgB, whB0[2], h0p[1]);  PKFMA_HI(xgB2, whB0[3], h0p[1]);
            PKFMA_LO(xgB, whB0[4], h0p[2]);  PKFMA_HI(xgB2, whB0[5], h0p[2]);

            c1 = fmaf(f1, c1, i1 * g1);
            float h1 = o1 * tanh_pre(TL2E * c1);

            GATHER(h1p, h1);

            // -- rotate x prefetch
            xq[j][0] = nx0; xq[j][1] = nx1; xq[j][2] = nx2;
        }
    }

    // ---- epilogue: FC for t = 511 (h1p holds h1(511)), flush last 4
    FC_BLOCK(ybuf[3]);
    if (live && ((L & 11) == 0)) {
        float4 yv = make_float4(ybuf[0], ybuf[1], ybuf[2], ybuf[3]);
        *(float4*)(op + 508) = yv;
    }
}

extern "C" void kernel_launch(void* const* d_in, const int* in_sizes, int n_in,
                              void* d_out, int out_size, void* d_ws, size_t ws_size,
                              hipStream_t stream) {
    const float* x     = (const float*)d_in[0];
    const float* wih0  = (const float*)d_in[1];
    const float* whh0  = (const float*)d_in[2];
    const float* bih0  = (const float*)d_in[3];
    const float* bhh0  = (const float*)d_in[4];
    const float* wih1  = (const float*)d_in[5];
    const float* whh1  = (const float*)d_in[6];
    const float* bih1  = (const float*)d_in[7];
    const float* bhh1  = (const float*)d_in[8];
    const float* fc1w  = (const float*)d_in[9];
    const float* fc1b  = (const float*)d_in[10];
    const float* fc2w  = (const float*)d_in[11];
    const float* fc2b  = (const float*)d_in[12];
    float* out = (float*)d_out;

    const int nbatch = in_sizes[0] / (512 * 6);     // 8192
    const int grid   = (nbatch + 7) / 8;            // 8 seqs per 64-thread wave

    hipLaunchKernelGGL(lstm_dpp8v12, dim3(grid), dim3(64), 0, stream,
                       x, wih0, whh0, bih0, bhh0, wih1, whh1, bih1, bhh1,
                       fc1w, fc1b, fc2w, fc2b, out, nbatch);
}

// Round 13
// 179.417 us; speedup vs baseline: 1.4959x; 1.0267x over previous
//
#include <hip/hip_runtime.h>

// RIIDModelLSTM: 2-layer LSTM (H=6), T=512, B=8192, fused FC(6->32->1) head.
//
// v13 = v10 (181.2us, best) + GATE0 EXP-HOIST.
// Ledger: 849 cyc/step = 658 busy (instruction-census floor) + ~190 serial-
// chain residue. R12's FC-deferral regressed (scheduler displacement);
// R11/R12 arithmetic closed the occupancy door (any >1-chain-per-wave shape
// needs 2x the seqs to keep 1024 waves; 512 fat waves = 2x wall). Remaining
// clean shave: v10's invariant makes gates0(t+1) FULLY closed at the end of
// step t (bias + x-part + wh-part all accumulated), yet the 2 pk_adds and
// 4 v_exp2 still headed step t+1's critical chain. v13 closes gates and
// issues the 4 exps at step t's tail; step t+1 opens directly with 4 rcps.
// Bit-identical arithmetic (same ops, same per-value order, earlier issue).
// Mapping unchanged: 8-lane coset/seq, p=(l&3)|((l>>3)<<2), zero-DS,
// DPP-only, pk-asm math, 1024 waves = 1/SIMD.

typedef float v2f __attribute__((ext_vector_type(2)));

static constexpr float L2E  = 1.44269504088896340736f;
static constexpr float TL2E = 2.0f * L2E;

#define DPP_QP(a,b,c,d) ((a)|((b)<<2)|((c)<<4)|((d)<<6))
#define DPP_X1  DPP_QP(1,0,3,2)   // quad_perm xor-1
#define DPP_X2  DPP_QP(2,3,0,1)   // quad_perm xor-2
#define DPP_B0  DPP_QP(0,0,0,0)   // quad bcast lane0
#define DPP_B1  DPP_QP(1,1,1,1)
#define DPP_B2  DPP_QP(2,2,2,2)
#define DPP_B3  DPP_QP(3,3,3,3)
#define DPP_X8  0x128             // row_ror:8 = lane xor 8 inside 16-row

template<int CTRL>
__device__ __forceinline__ float dppf(float v) {
    return __int_as_float(__builtin_amdgcn_update_dpp(
        0, __float_as_int(v), CTRL, 0xF, 0xF, true));
}

#define PIN(v) asm volatile("" : "+v"(v))

// d += a * (b.lo, b.lo)   [VOP3P op_sel: src1 lo for both halves]
#define PKFMA_LO(d,a,b) asm("v_pk_fma_f32 %0, %1, %2, %0 op_sel:[0,0,0] op_sel_hi:[1,0,1]" : "+v"(d) : "v"(a), "v"(b))
// d += a * (b.hi, b.hi)
#define PKFMA_HI(d,a,b) asm("v_pk_fma_f32 %0, %1, %2, %0 op_sel:[0,1,0] op_sel_hi:[1,1,1]" : "+v"(d) : "v"(a), "v"(b))
#define PKADD(d,a,b)    asm("v_pk_add_f32 %0, %1, %2" : "=v"(d) : "v"(a), "v"(b))

// sigmoid from a pre-computed e = exp2(-L2E*x):  1/(1+e)
__device__ __forceinline__ float sig_from_e(float e) {
    return __builtin_amdgcn_rcpf(1.0f + e);
}
// tanh from e = exp2(2*L2E*x):  1 - 2/(1+e)
__device__ __forceinline__ float tanh_from_e(float e) {
    return fmaf(-2.0f, __builtin_amdgcn_rcpf(1.0f + e), 1.0f);
}
// full forms (used for cell-1 gates and tanh(c), which can't be hoisted)
__device__ __forceinline__ float sig_pre(float a) {
    return __builtin_amdgcn_rcpf(1.0f + __builtin_amdgcn_exp2f(a));
}
__device__ __forceinline__ float tanh_pre(float a) {
    return fmaf(-2.0f, __builtin_amdgcn_rcpf(1.0f + __builtin_amdgcn_exp2f(a)), 1.0f);
}

extern "C" __global__ void __launch_bounds__(64)
__attribute__((amdgpu_waves_per_eu(1, 1)))
lstm_dpp8v13(const float* __restrict__ x,
             const float* __restrict__ wih0, const float* __restrict__ whh0,
             const float* __restrict__ bih0, const float* __restrict__ bhh0,
             const float* __restrict__ wih1, const float* __restrict__ whh1,
             const float* __restrict__ bih1, const float* __restrict__ bhh1,
             const float* __restrict__ fc1w, const float* __restrict__ fc1b,
             const float* __restrict__ fc2w, const float* __restrict__ fc2b,
             float* __restrict__ out, int nbatch)
{
    const int L   = threadIdx.x;                 // 0..63
    const int l   = L & 15;
    const int row = L >> 4;                      // 0..3
    const int cst = (l >> 2) & 1;                // coset within row
    const int p   = (l & 3) | ((l >> 3) << 2);   // position in coset, 0..7
    const bool lowq = ((L >> 3) & 1) == 0;       // lane in units-0..3 quad

    int seq = blockIdx.x * 8 + row * 2 + cst;
    const bool live = (seq < nbatch);
    if (!live) seq = nbatch - 1;

    const float km = (p < 6) ? 1.0f : 0.0f;      // pad lanes 6,7
    const int   k  = (p < 6) ? p : 0;
    const int ir = k, fr = 6 + k, gr = 12 + k, orr = 18 + k;  // i,f,g,o rows

    // ---- weights. Gate pairs A=[i,f] (sigmoid,-L2E | sigmoid,-L2E),
    //               B=[g,o] (tanh,+2L2E | sigmoid,-L2E). Unit-ordered slots.
    v2f wiA0[6], wiB0[6];
    v2f whA0[6], whB0[6], wiA1[6], wiB1[6], whA1[6], whB1[6], f1wA[6], f1wB[6];
#pragma unroll
    for (int j = 0; j < 6; ++j) {
        wiA0[j] = (v2f){ wih0[ir*6+j]*(-L2E)*km,  wih0[fr*6+j]*(-L2E)*km };
        wiB0[j] = (v2f){ wih0[gr*6+j]*( TL2E)*km, wih0[orr*6+j]*(-L2E)*km };
        whA0[j] = (v2f){ whh0[ir*6+j]*(-L2E)*km,  whh0[fr*6+j]*(-L2E)*km };
        whB0[j] = (v2f){ whh0[gr*6+j]*( TL2E)*km, whh0[orr*6+j]*(-L2E)*km };
        wiA1[j] = (v2f){ wih1[ir*6+j]*(-L2E)*km,  wih1[fr*6+j]*(-L2E)*km };
        wiB1[j] = (v2f){ wih1[gr*6+j]*( TL2E)*km, wih1[orr*6+j]*(-L2E)*km };
        whA1[j] = (v2f){ whh1[ir*6+j]*(-L2E)*km,  whh1[fr*6+j]*(-L2E)*km };
        whB1[j] = (v2f){ whh1[gr*6+j]*( TL2E)*km, whh1[orr*6+j]*(-L2E)*km };
        f1wA[j] = (v2f){ fc1w[(4*p+0)*6+j], fc1w[(4*p+1)*6+j] };
        f1wB[j] = (v2f){ fc1w[(4*p+2)*6+j], fc1w[(4*p+3)*6+j] };
    }
    v2f bbA0 = (v2f){ (bih0[ir]+bhh0[ir])*(-L2E)*km,  (bih0[fr]+bhh0[fr])*(-L2E)*km };
    v2f bbB0 = (v2f){ (bih0[gr]+bhh0[gr])*( TL2E)*km, (bih0[orr]+bhh0[orr])*(-L2E)*km };
    v2f bbA1 = (v2f){ (bih1[ir]+bhh1[ir])*(-L2E)*km,  (bih1[fr]+bhh1[fr])*(-L2E)*km };
    v2f bbB1 = (v2f){ (bih1[gr]+bhh1[gr])*( TL2E)*km, (bih1[orr]+bhh1[orr])*(-L2E)*km };
    v2f f1bA = (v2f){ fc1b[4*p+0], fc1b[4*p+1] };
    v2f f1bB = (v2f){ fc1b[4*p+2], fc1b[4*p+3] };
    v2f f2wA = (v2f){ fc2w[4*p+0], fc2w[4*p+1] };
    v2f f2wB = (v2f){ fc2w[4*p+2], fc2w[4*p+3] };
    float f2b = fc2b[0];

#pragma unroll
    for (int j = 0; j < 6; ++j) {
        PIN(wiA0[j]); PIN(wiB0[j]); PIN(whA0[j]); PIN(whB0[j]);
        PIN(wiA1[j]); PIN(wiB1[j]); PIN(whA1[j]); PIN(whB1[j]);
        PIN(f1wA[j]); PIN(f1wB[j]);
    }
    PIN(bbA0); PIN(bbB0); PIN(bbA1); PIN(bbB1);
    PIN(f1bA); PIN(f1bB); PIN(f2wA); PIN(f2wB); PIN(f2b);

    // ---- state: h packed pairwise, units (0,1),(2,3),(4,5)
    v2f h0p[3], h1p[3];
    const v2f Z2 = (v2f){0.0f, 0.0f};
#pragma unroll
    for (int q = 0; q < 3; ++q) { h0p[q] = Z2; h1p[q] = Z2; }
    float c0 = 0.0f, c1 = 0.0f;

    const float* xp = x + (size_t)seq * (512 * 6);
    float*       op = out + (size_t)seq * 512;

    // ---- 4-deep x prefetch, pairs (x0,x1),(x2,x3),(x4,x5) as v2f
    v2f xq[4][3];
#pragma unroll
    for (int j = 0; j < 4; ++j) {
        const float* q = xp + j * 6;
        xq[j][0] = *(const v2f*)(q + 0);
        xq[j][1] = *(const v2f*)(q + 2);
        xq[j][2] = *(const v2f*)(q + 4);
    }

    // unit-ordered gather: h[unit j] -> slot j on every lane, 6 slots
#define GATHER(HP_, HV_)                                                        \
    {                                                                           \
        float u_ = dppf<DPP_X8>(HV_);            /* partner quad's h */         \
        float hl = lowq ? (HV_) : u_;            /* units 0-3 @ quad pos */     \
        float hh = lowq ? u_ : (HV_);            /* units 4-7 @ quad pos */     \
        HP_[0] = (v2f){ dppf<DPP_B0>(hl), dppf<DPP_B1>(hl) };                   \
        HP_[1] = (v2f){ dppf<DPP_B2>(hl), dppf<DPP_B3>(hl) };                   \
        HP_[2] = (v2f){ dppf<DPP_B0>(hh), dppf<DPP_B1>(hh) };                   \
    }

    // ---- cell0 gate-preactivation accumulators + HOISTED exps for step 0.
    // Prologue: bias + x(0)-part (wh-part is zero since h0(-1)=0), then
    // close gates and issue their exps (the v13 hoist, applied to t=0 too).
    v2f xgA, xgA2, xgB, xgB2;
    float exi, exf, exg, exo;     // exp2 of gate0 preacts for the NEXT step
    {
        xgA = bbA0; xgA2 = Z2; xgB = bbB0; xgB2 = Z2;
        PKFMA_LO(xgA, wiA0[0], xq[0][0]); PKFMA_HI(xgA2, wiA0[1], xq[0][0]);
        PKFMA_LO(xgA, wiA0[2], xq[0][1]); PKFMA_HI(xgA2, wiA0[3], xq[0][1]);
        PKFMA_LO(xgA, wiA0[4], xq[0][2]); PKFMA_HI(xgA2, wiA0[5], xq[0][2]);
        PKFMA_LO(xgB, wiB0[0], xq[0][0]); PKFMA_HI(xgB2, wiB0[1], xq[0][0]);
        PKFMA_LO(xgB, wiB0[2], xq[0][1]); PKFMA_HI(xgB2, wiB0[3], xq[0][1]);
        PKFMA_LO(xgB, wiB0[4], xq[0][2]); PKFMA_HI(xgB2, wiB0[5], xq[0][2]);
        v2f gA0, gB0;
        PKADD(gA0, xgA, xgA2);
        PKADD(gB0, xgB, xgB2);
        exi = __builtin_amdgcn_exp2f(gA0.x);
        exf = __builtin_amdgcn_exp2f(gA0.y);
        exg = __builtin_amdgcn_exp2f(gB0.x);
        exo = __builtin_amdgcn_exp2f(gB0.y);
    }

    float y[4];

    for (int T = 0; T < 512; T += 4) {
        const int Tn = (T < 508) ? T + 4 : 508;   // clamped prefetch base
#pragma unroll
        for (int j = 0; j < 4; ++j) {
            // -- issue x[T+j+4] loads early (consumed next outer iter)
            const float* xr = xp + (Tn + j) * 6;
            v2f nx0 = *(const v2f*)(xr + 0);
            v2f nx1 = *(const v2f*)(xr + 2);
            v2f nx2 = *(const v2f*)(xr + 4);

            // -- act0 opens DIRECTLY with rcps (exps hoisted to prev step)
            float i0 = sig_from_e(exi), f0 = sig_from_e(exf);
            float g0 = tanh_from_e(exg), o0 = sig_from_e(exo);

            // -- act0-window filler 1: cell1 recurrent partial (h1p(t-1))
            v2f pA = bbA1, pA2 = Z2, pB = bbB1, pB2 = Z2;
            PKFMA_LO(pA, whA1[0], h1p[0]); PKFMA_HI(pA2, whA1[1], h1p[0]);
            PKFMA_LO(pA, whA1[2], h1p[1]); PKFMA_HI(pA2, whA1[3], h1p[1]);
            PKFMA_LO(pA, whA1[4], h1p[2]); PKFMA_HI(pA2, whA1[5], h1p[2]);
            PKFMA_LO(pB, whB1[0], h1p[0]); PKFMA_HI(pB2, whB1[1], h1p[0]);
            PKFMA_LO(pB, whB1[2], h1p[1]); PKFMA_HI(pB2, whB1[3], h1p[1]);
            PKFMA_LO(pB, whB1[4], h1p[2]); PKFMA_HI(pB2, whB1[5], h1p[2]);

            // -- act0-window filler 2: x-part of gates0(t+1) into fresh regs
            {
                const v2f* xn = xq[(j + 1) & 3];
                v2f tA = bbA0, tA2 = Z2, tB = bbB0, tB2 = Z2;
                PKFMA_LO(tA, wiA0[0], xn[0]); PKFMA_HI(tA2, wiA0[1], xn[0]);
                PKFMA_LO(tA, wiA0[2], xn[1]); PKFMA_HI(tA2, wiA0[3], xn[1]);
                PKFMA_LO(tA, wiA0[4], xn[2]); PKFMA_HI(tA2, wiA0[5], xn[2]);
                PKFMA_LO(tB, wiB0[0], xn[0]); PKFMA_HI(tB2, wiB0[1], xn[0]);
                PKFMA_LO(tB, wiB0[2], xn[1]); PKFMA_HI(tB2, wiB0[3], xn[1]);
                PKFMA_LO(tB, wiB0[4], xn[2]); PKFMA_HI(tB2, wiB0[5], xn[2]);
                xgA = tA; xgA2 = tA2; xgB = tB; xgB2 = tB2;
            }

            c0 = fmaf(f0, c0, i0 * g0);
            float h0 = o0 * tanh_pre(TL2E * c0);

            GATHER(h0p, h0);

            // -- cell 1 finish (input part over fresh h0)
            PKFMA_LO(pA, wiA1[0], h0p[0]); PKFMA_HI(pA2, wiA1[1], h0p[0]);
            PKFMA_LO(pA, wiA1[2], h0p[1]); PKFMA_HI(pA2, wiA1[3], h0p[1]);
            PKFMA_LO(pA, wiA1[4], h0p[2]); PKFMA_HI(pA2, wiA1[5], h0p[2]);
            PKFMA_LO(pB, wiB1[0], h0p[0]); PKFMA_HI(pB2, wiB1[1], h0p[0]);
            PKFMA_LO(pB, wiB1[2], h0p[1]); PKFMA_HI(pB2, wiB1[3], h0p[1]);
            PKFMA_LO(pB, wiB1[4], h0p[2]); PKFMA_HI(pB2, wiB1[5], h0p[2]);
            v2f gA1, gB1;
            PKADD(gA1, pA, pA2);
            PKADD(gB1, pB, pB2);

            float i1 = sig_pre(gA1.x), f1 = sig_pre(gA1.y);
            float g1 = tanh_pre(gB1.x), o1 = sig_pre(gB1.y);

            // -- act1-window filler: wh-part of gates0(t+1) (h0p = h0(t))
            PKFMA_LO(xgA, whA0[0], h0p[0]);  PKFMA_HI(xgA2, whA0[1], h0p[0]);
            PKFMA_LO(xgA, whA0[2], h0p[1]);  PKFMA_HI(xgA2, whA0[3], h0p[1]);
            PKFMA_LO(xgA, whA0[4], h0p[2]);  PKFMA_HI(xgA2, whA0[5], h0p[2]);
            PKFMA_LO(xgB, whB0[0], h0p[0]);  PKFMA_HI(xgB2, whB0[1], h0p[0]);
            PKFMA_LO(xgB, whB0[2], h0p[1]);  PKFMA_HI(xgB2, whB0[3], h0p[1]);
            PKFMA_LO(xgB, whB0[4], h0p[2]);  PKFMA_HI(xgB2, whB0[5], h0p[2]);

            c1 = fmaf(f1, c1, i1 * g1);
            float h1 = o1 * tanh_pre(TL2E * c1);

            GATHER(h1p, h1);

            // -- THE v13 HOIST: close gates0(t+1) and issue its 4 exps now,
            //    off next step's critical chain. Bit-identical values.
            {
                v2f gA0n, gB0n;
                PKADD(gA0n, xgA, xgA2);
                PKADD(gB0n, xgB, xgB2);
                exi = __builtin_amdgcn_exp2f(gA0n.x);
                exf = __builtin_amdgcn_exp2f(gA0n.y);
                exg = __builtin_amdgcn_exp2f(gB0n.x);
                exo = __builtin_amdgcn_exp2f(gB0n.y);
            }

            // -- FC head on fresh h1 (fills the exp-hoist latency window)
            v2f rA = f1bA, rA2 = Z2, rB = f1bB, rB2 = Z2;
            PKFMA_LO(rA, f1wA[0], h1p[0]); PKFMA_HI(rA2, f1wA[1], h1p[0]);
            PKFMA_LO(rA, f1wA[2], h1p[1]); PKFMA_HI(rA2, f1wA[3], h1p[1]);
            PKFMA_LO(rA, f1wA[4], h1p[2]); PKFMA_HI(rA2, f1wA[5], h1p[2]);
            PKFMA_LO(rB, f1wB[0], h1p[0]); PKFMA_HI(rB2, f1wB[1], h1p[0]);
            PKFMA_LO(rB, f1wB[2], h1p[1]); PKFMA_HI(rB2, f1wB[3], h1p[1]);
            PKFMA_LO(rB, f1wB[4], h1p[2]); PKFMA_HI(rB2, f1wB[5], h1p[2]);
            v2f RA, RB;
            PKADD(RA, rA, rA2);
            PKADD(RB, rB, rB2);
            float acc =          fmaxf(RA.x, 0.0f) * f2wA.x;
            acc = fmaf(fmaxf(RA.y, 0.0f), f2wA.y, acc);
            acc = fmaf(fmaxf(RB.x, 0.0f), f2wB.x, acc);
            acc = fmaf(fmaxf(RB.y, 0.0f), f2wB.y, acc);
            // butterfly reduce over the 8-lane coset (pure VALU)
            acc += dppf<DPP_X1>(acc);
            acc += dppf<DPP_X2>(acc);
            acc += dppf<DPP_X8>(acc);
            y[j] = fmaxf(acc + f2b, 0.0f);

            // -- rotate x prefetch
            xq[j][0] = nx0; xq[j][1] = nx1; xq[j][2] = nx2;
        }
        // -- one coalesced 16B out-store per 4 steps (lane p==0 of each coset)
        if (live && ((L & 11) == 0)) {
            float4 yv = make_float4(y[0], y[1], y[2], y[3]);
            *(float4*)(op + T) = yv;
        }
    }
}

extern "C" void kernel_launch(void* const* d_in, const int* in_sizes, int n_in,
                              void* d_out, int out_size, void* d_ws, size_t ws_size,
                              hipStream_t stream) {
    const float* x     = (const float*)d_in[0];
    const float* wih0  = (const float*)d_in[1];
    const float* whh0  = (const float*)d_in[2];
    const float* bih0  = (const float*)d_in[3];
    const float* bhh0  = (const float*)d_in[4];
    const float* wih1  = (const float*)d_in[5];
    const float* whh1  = (const float*)d_in[6];
    const float* bih1  = (const float*)d_in[7];
    const float* bhh1  = (const float*)d_in[8];
    const float* fc1w  = (const float*)d_in[9];
    const float* fc1b  = (const float*)d_in[10];
    const float* fc2w  = (const float*)d_in[11];
    const float* fc2b  = (const float*)d_in[12];
    float* out = (float*)d_out;

    const int nbatch = in_sizes[0] / (512 * 6);     // 8192
    const int grid   = (nbatch + 7) / 8;            // 8 seqs per 64-thread wave

    hipLaunchKernelGGL(lstm_dpp8v13, dim3(grid), dim3(64), 0, stream,
                       x, wih0, whh0, bih0, bhh0, wih1, whh1, bih1, bhh1,
                       fc1w, fc1b, fc2w, fc2b, out, nbatch);
}